// Round 1
// baseline (1835.374 us; speedup 1.0000x reference)
//
#include <hip/hip_runtime.h>

#define N_NODES 100000
#define N_EDGES 1600000
#define CH 128
#define OCH 64

// ---------------- degree / normalization ----------------

__global__ void k_deg_init(float* __restrict__ deg) {
    int i = blockIdx.x * blockDim.x + threadIdx.x;
    if (i < N_NODES) deg[i] = 1.0f;  // self-loop
}

__global__ void k_deg_count(const int* __restrict__ dst, float* __restrict__ deg) {
    int i = blockIdx.x * blockDim.x + threadIdx.x;
    if (i < N_EDGES) atomicAdd(&deg[dst[i]], 1.0f);
}

__global__ void k_dis(float* __restrict__ deg) {
    int i = blockIdx.x * blockDim.x + threadIdx.x;
    if (i < N_NODES) deg[i] = rsqrtf(deg[i]);
}

__global__ void k_edge_norm(const int* __restrict__ src, const int* __restrict__ dst,
                            const float* __restrict__ dis, float* __restrict__ norm) {
    int i = blockIdx.x * blockDim.x + threadIdx.x;
    if (i < N_EDGES) norm[i] = dis[src[i]] * dis[dst[i]];
}

// ---------------- GEMM: out[N][128] = A[N][128] @ W[128][128] ----------------
// 32-row tile per block; 256 threads; each thread computes 4 rows x 4 cols.
// W staged in LDS in two 64-k halves (keeps static LDS at 48KB -> 3 blocks/CU).

__global__ __launch_bounds__(256) void k_gemm128(const float* __restrict__ A,
                                                 const float* __restrict__ W,
                                                 float* __restrict__ out) {
    __shared__ float sW[64 * 128];
    __shared__ float sA[32][128];

    const int tx = threadIdx.x & 31;  // col group: cols 4tx..4tx+3
    const int ty = threadIdx.x >> 5;  // row group: rows 4ty..4ty+3
    const int row0 = blockIdx.x * 32; // 100000 = 32*3125 exact

    for (int i = threadIdx.x; i < 32 * 128; i += 256) {
        int r = i >> 7, k = i & 127;
        sA[r][k] = A[(size_t)(row0 + r) * CH + k];
    }

    float acc[4][4] = {};
    for (int kh = 0; kh < 2; ++kh) {
        __syncthreads();
        for (int i = threadIdx.x; i < 64 * 128; i += 256)
            sW[i] = W[kh * 64 * 128 + i];
        __syncthreads();
        const int kbase = kh * 64;
#pragma unroll 4
        for (int k = 0; k < 64; k += 4) {
            float4 w0 = *(const float4*)&sW[(k + 0) * 128 + 4 * tx];
            float4 w1 = *(const float4*)&sW[(k + 1) * 128 + 4 * tx];
            float4 w2 = *(const float4*)&sW[(k + 2) * 128 + 4 * tx];
            float4 w3 = *(const float4*)&sW[(k + 3) * 128 + 4 * tx];
#pragma unroll
            for (int j = 0; j < 4; ++j) {
                float4 a = *(const float4*)&sA[4 * ty + j][kbase + k];
                acc[j][0] += a.x * w0.x + a.y * w1.x + a.z * w2.x + a.w * w3.x;
                acc[j][1] += a.x * w0.y + a.y * w1.y + a.z * w2.y + a.w * w3.y;
                acc[j][2] += a.x * w0.z + a.y * w1.z + a.z * w2.z + a.w * w3.z;
                acc[j][3] += a.x * w0.w + a.y * w1.w + a.z * w2.w + a.w * w3.w;
            }
        }
    }
#pragma unroll
    for (int j = 0; j < 4; ++j) {
        float4 o = {acc[j][0], acc[j][1], acc[j][2], acc[j][3]};
        *(float4*)&out[(size_t)(row0 + 4 * ty + j) * CH + 4 * tx] = o;
    }
}

// ---------------- aggregation ----------------
// out[v][c] = b[c] + dis[v]^2 * h[v][c]   (self-loop + bias init)

__global__ void k_agg_init(const float* __restrict__ h, const float* __restrict__ dis,
                           const float* __restrict__ b, float* __restrict__ out) {
    int g = blockIdx.x * blockDim.x + threadIdx.x;  // over N*32
    if (g >= N_NODES * 32) return;
    int v = g >> 5, c4 = (g & 31) * 4;
    float s = dis[v];
    s = s * s;
    float4 hv = *(const float4*)&h[(size_t)v * CH + c4];
    float4 bv = *(const float4*)&b[c4];
    float4 o = {s * hv.x + bv.x, s * hv.y + bv.y, s * hv.z + bv.z, s * hv.w + bv.w};
    *(float4*)&out[(size_t)v * CH + c4] = o;
}

// out[dst[e]][c] += norm[e] * h[src[e]][c]  via atomics (round-0 baseline)
__global__ void k_agg_edges(const int* __restrict__ src, const int* __restrict__ dst,
                            const float* __restrict__ norm, const float* __restrict__ h,
                            float* __restrict__ out) {
    int g = blockIdx.x * blockDim.x + threadIdx.x;  // over E*128 = 204.8M < 2^31
    int e = g >> 7, c = g & 127;
    float v = norm[e] * h[(size_t)src[e] * CH + c];
    atomicAdd(&out[(size_t)dst[e] * CH + c], v);
}

__global__ void k_relu(float* __restrict__ x) {
    int g = blockIdx.x * blockDim.x + threadIdx.x;  // over N*32
    if (g >= N_NODES * 32) return;
    float4 v = *(float4*)&x[(size_t)g * 4];
    v.x = fmaxf(v.x, 0.f); v.y = fmaxf(v.y, 0.f);
    v.z = fmaxf(v.z, 0.f); v.w = fmaxf(v.w, 0.f);
    *(float4*)&x[(size_t)g * 4] = v;
}

// ---------------- final: out[N][64] = (x1+x2)[N][128] @ Wo[128][64] + bo ----------------
// 16 rows per block; thread t: row ty=t/16, cols 4*(t%16)..+3

__global__ __launch_bounds__(256) void k_final(const float* __restrict__ x1,
                                               const float* __restrict__ x2,
                                               const float* __restrict__ Wo,
                                               const float* __restrict__ bo,
                                               float* __restrict__ out) {
    __shared__ float sW[128 * 64];
    __shared__ float sb[64];
    for (int i = threadIdx.x; i < 128 * 64; i += 256) sW[i] = Wo[i];
    if (threadIdx.x < 64) sb[threadIdx.x] = bo[threadIdx.x];
    __syncthreads();

    const int tx = threadIdx.x & 15, ty = threadIdx.x >> 4;
    const int row = blockIdx.x * 16 + ty;  // 100000 = 16*6250 exact
    const float* p1 = &x1[(size_t)row * CH];
    const float* p2 = &x2[(size_t)row * CH];
    float4 acc = {sb[4 * tx], sb[4 * tx + 1], sb[4 * tx + 2], sb[4 * tx + 3]};
#pragma unroll 8
    for (int k = 0; k < 128; ++k) {
        float a = p1[k] + p2[k];
        float4 w = *(const float4*)&sW[k * 64 + 4 * tx];
        acc.x += a * w.x; acc.y += a * w.y; acc.z += a * w.z; acc.w += a * w.w;
    }
    *(float4*)&out[(size_t)row * OCH + 4 * tx] = acc;
}

// ---------------- launch ----------------

extern "C" void kernel_launch(void* const* d_in, const int* in_sizes, int n_in,
                              void* d_out, int out_size, void* d_ws, size_t ws_size,
                              hipStream_t stream) {
    const float* x  = (const float*)d_in[0];
    const int*   ei = (const int*)d_in[1];
    const int*   src = ei;
    const int*   dst = ei + N_EDGES;
    const float* W1 = (const float*)d_in[2];
    const float* b1 = (const float*)d_in[3];
    const float* W2 = (const float*)d_in[4];
    const float* b2 = (const float*)d_in[5];
    const float* Wo = (const float*)d_in[6];
    const float* bo = (const float*)d_in[7];
    float* out = (float*)d_out;

    char* ws = (char*)d_ws;
    float* dis  = (float*)ws;                              // 400,000 B
    float* norm = (float*)(ws + 400000);                   // 6,400,000 B
    float* h    = (float*)(ws + 400000 + 6400000);         // 51.2 MB
    float* x1   = h  + (size_t)N_NODES * CH;               // 51.2 MB
    float* x2   = x1 + (size_t)N_NODES * CH;               // 51.2 MB

    const int B = 256;
    // normalization (graph-static, but recomputed every call as required)
    k_deg_init<<<(N_NODES + B - 1) / B, B, 0, stream>>>(dis);
    k_deg_count<<<(N_EDGES + B - 1) / B, B, 0, stream>>>(dst, dis);
    k_dis<<<(N_NODES + B - 1) / B, B, 0, stream>>>(dis);
    k_edge_norm<<<(N_EDGES + B - 1) / B, B, 0, stream>>>(src, dst, dis, norm);

    // layer 1
    k_gemm128<<<N_NODES / 32, B, 0, stream>>>(x, W1, h);
    k_agg_init<<<N_NODES * 32 / B, B, 0, stream>>>(h, dis, b1, x1);
    k_agg_edges<<<(int)((size_t)N_EDGES * CH / B), B, 0, stream>>>(src, dst, norm, h, x1);
    k_relu<<<N_NODES * 32 / B, B, 0, stream>>>(x1);

    // layer 2
    k_gemm128<<<N_NODES / 32, B, 0, stream>>>(x1, W2, h);
    k_agg_init<<<N_NODES * 32 / B, B, 0, stream>>>(h, dis, b2, x2);
    k_agg_edges<<<(int)((size_t)N_EDGES * CH / B), B, 0, stream>>>(src, dst, norm, h, x2);
    k_relu<<<N_NODES * 32 / B, B, 0, stream>>>(x2);

    // output projection
    k_final<<<N_NODES / 16, B, 0, stream>>>(x1, x2, Wo, bo, out);
}

// Round 2
// 805.689 us; speedup vs baseline: 2.2780x; 2.2780x over previous
//
#include <hip/hip_runtime.h>

#define N_NODES 100000
#define N_EDGES 1600000
#define CH 128
#define OCH 64
#define NB_SCAN 391  // ceil(100000/256)

// ---------------- CSR build ----------------

__global__ void k_init(int* __restrict__ cnt, int* __restrict__ fill) {
    int i = blockIdx.x * blockDim.x + threadIdx.x;
    if (i < N_NODES) { cnt[i] = 0; fill[i] = 0; }
}

__global__ void k_count(const int* __restrict__ dst, int* __restrict__ cnt) {
    int i = blockIdx.x * blockDim.x + threadIdx.x;
    if (i < N_EDGES) atomicAdd(&cnt[dst[i]], 1);
}

__global__ void k_dis(const int* __restrict__ cnt, float* __restrict__ dis) {
    int i = blockIdx.x * blockDim.x + threadIdx.x;
    if (i < N_NODES) dis[i] = rsqrtf((float)(cnt[i] + 1));  // +1 self-loop
}

// hierarchical exclusive scan of cnt -> rowptr
__global__ void k_scan1(const int* __restrict__ cnt, int* __restrict__ rowptr,
                        int* __restrict__ bsum) {
    __shared__ int tmp[256];
    int i = blockIdx.x * 256 + threadIdx.x;
    int v = (i < N_NODES) ? cnt[i] : 0;
    tmp[threadIdx.x] = v;
    __syncthreads();
    for (int off = 1; off < 256; off <<= 1) {
        int t = (threadIdx.x >= off) ? tmp[threadIdx.x - off] : 0;
        __syncthreads();
        tmp[threadIdx.x] += t;
        __syncthreads();
    }
    if (i < N_NODES) rowptr[i] = tmp[threadIdx.x] - v;  // exclusive
    if (threadIdx.x == 255) bsum[blockIdx.x] = tmp[255];
}

__global__ void k_scan2(int* __restrict__ bsum) {
    __shared__ int tmp[512];
    int v = (threadIdx.x < NB_SCAN) ? bsum[threadIdx.x] : 0;
    tmp[threadIdx.x] = v;
    __syncthreads();
    for (int off = 1; off < 512; off <<= 1) {
        int t = (threadIdx.x >= off) ? tmp[threadIdx.x - off] : 0;
        __syncthreads();
        tmp[threadIdx.x] += t;
        __syncthreads();
    }
    if (threadIdx.x < NB_SCAN) bsum[threadIdx.x] = tmp[threadIdx.x] - v;
}

__global__ void k_scan3(int* __restrict__ rowptr, const int* __restrict__ bsum) {
    int i = blockIdx.x * 256 + threadIdx.x;
    if (i < N_NODES) rowptr[i] += bsum[blockIdx.x];
    if (i == 0) rowptr[N_NODES] = N_EDGES;
}

__global__ void k_scatter(const int* __restrict__ src, const int* __restrict__ dst,
                          const int* __restrict__ rowptr, int* __restrict__ fill,
                          const float* __restrict__ dis,
                          int* __restrict__ esrc, float* __restrict__ eval) {
    int e = blockIdx.x * blockDim.x + threadIdx.x;
    if (e >= N_EDGES) return;
    int s = src[e], d = dst[e];
    int pos = rowptr[d] + atomicAdd(&fill[d], 1);
    esrc[pos] = s;
    eval[pos] = dis[s] * dis[d];
}

// ---------------- GEMM: out[N][128] = A[N][128] @ W[128][128] ----------------

__global__ __launch_bounds__(256) void k_gemm128(const float* __restrict__ A,
                                                 const float* __restrict__ W,
                                                 float* __restrict__ out) {
    __shared__ float sW[64 * 128];
    __shared__ float sA[32][128];

    const int tx = threadIdx.x & 31;
    const int ty = threadIdx.x >> 5;
    const int row0 = blockIdx.x * 32;

    for (int i = threadIdx.x; i < 32 * 128; i += 256) {
        int r = i >> 7, k = i & 127;
        sA[r][k] = A[(size_t)(row0 + r) * CH + k];
    }

    float acc[4][4] = {};
    for (int kh = 0; kh < 2; ++kh) {
        __syncthreads();
        for (int i = threadIdx.x; i < 64 * 128; i += 256)
            sW[i] = W[kh * 64 * 128 + i];
        __syncthreads();
        const int kbase = kh * 64;
#pragma unroll 4
        for (int k = 0; k < 64; k += 4) {
            float4 w0 = *(const float4*)&sW[(k + 0) * 128 + 4 * tx];
            float4 w1 = *(const float4*)&sW[(k + 1) * 128 + 4 * tx];
            float4 w2 = *(const float4*)&sW[(k + 2) * 128 + 4 * tx];
            float4 w3 = *(const float4*)&sW[(k + 3) * 128 + 4 * tx];
#pragma unroll
            for (int j = 0; j < 4; ++j) {
                float4 a = *(const float4*)&sA[4 * ty + j][kbase + k];
                acc[j][0] += a.x * w0.x + a.y * w1.x + a.z * w2.x + a.w * w3.x;
                acc[j][1] += a.x * w0.y + a.y * w1.y + a.z * w2.y + a.w * w3.y;
                acc[j][2] += a.x * w0.z + a.y * w1.z + a.z * w2.z + a.w * w3.z;
                acc[j][3] += a.x * w0.w + a.y * w1.w + a.z * w2.w + a.w * w3.w;
            }
        }
    }
#pragma unroll
    for (int j = 0; j < 4; ++j) {
        float4 o = {acc[j][0], acc[j][1], acc[j][2], acc[j][3]};
        *(float4*)&out[(size_t)(row0 + 4 * ty + j) * CH + 4 * tx] = o;
    }
}

// ---------------- CSR aggregation (fused bias + self-loop + relu) ----------------
// one wave per node; lane holds channels 2*lane, 2*lane+1

__global__ __launch_bounds__(256) void k_agg_csr(
    const int* __restrict__ rowptr, const int* __restrict__ esrc,
    const float* __restrict__ eval, const float* __restrict__ h,
    const float* __restrict__ dis, const float* __restrict__ bias,
    float* __restrict__ out) {
    int v = blockIdx.x * 4 + (threadIdx.x >> 6);  // 25000 blocks x 4 waves = 100000
    int lane = threadIdx.x & 63;
    int c2 = lane * 2;

    float s = dis[v];
    s = s * s;
    float2 acc = *(const float2*)&h[(size_t)v * CH + c2];
    float2 bv = *(const float2*)&bias[c2];
    acc.x = acc.x * s + bv.x;
    acc.y = acc.y * s + bv.y;

    int e = rowptr[v], e1 = rowptr[v + 1];
    for (; e + 1 < e1; e += 2) {
        int s0 = esrc[e], s1 = esrc[e + 1];
        float w0 = eval[e], w1 = eval[e + 1];
        float2 h0 = *(const float2*)&h[(size_t)s0 * CH + c2];
        float2 h1 = *(const float2*)&h[(size_t)s1 * CH + c2];
        acc.x += w0 * h0.x + w1 * h1.x;
        acc.y += w0 * h0.y + w1 * h1.y;
    }
    if (e < e1) {
        int s0 = esrc[e];
        float w0 = eval[e];
        float2 h0 = *(const float2*)&h[(size_t)s0 * CH + c2];
        acc.x += w0 * h0.x;
        acc.y += w0 * h0.y;
    }
    acc.x = fmaxf(acc.x, 0.f);
    acc.y = fmaxf(acc.y, 0.f);
    *(float2*)&out[(size_t)v * CH + c2] = acc;
}

// ---------------- final: out[N][64] = (x1+x2)[N][128] @ Wo[128][64] + bo ----------------

__global__ __launch_bounds__(256) void k_final(const float* __restrict__ x1,
                                               const float* __restrict__ x2,
                                               const float* __restrict__ Wo,
                                               const float* __restrict__ bo,
                                               float* __restrict__ out) {
    __shared__ float sW[128 * 64];
    __shared__ float sb[64];
    for (int i = threadIdx.x; i < 128 * 64; i += 256) sW[i] = Wo[i];
    if (threadIdx.x < 64) sb[threadIdx.x] = bo[threadIdx.x];
    __syncthreads();

    const int tx = threadIdx.x & 15, ty = threadIdx.x >> 4;
    const int row = blockIdx.x * 16 + ty;
    const float* p1 = &x1[(size_t)row * CH];
    const float* p2 = &x2[(size_t)row * CH];
    float4 acc = {sb[4 * tx], sb[4 * tx + 1], sb[4 * tx + 2], sb[4 * tx + 3]};
#pragma unroll 8
    for (int k = 0; k < 128; ++k) {
        float a = p1[k] + p2[k];
        float4 w = *(const float4*)&sW[k * 64 + 4 * tx];
        acc.x += a * w.x; acc.y += a * w.y; acc.z += a * w.z; acc.w += a * w.w;
    }
    *(float4*)&out[(size_t)row * OCH + 4 * tx] = acc;
}

// ---------------- launch ----------------

extern "C" void kernel_launch(void* const* d_in, const int* in_sizes, int n_in,
                              void* d_out, int out_size, void* d_ws, size_t ws_size,
                              hipStream_t stream) {
    const float* x  = (const float*)d_in[0];
    const int*   ei = (const int*)d_in[1];
    const int*   src = ei;
    const int*   dst = ei + N_EDGES;
    const float* W1 = (const float*)d_in[2];
    const float* b1 = (const float*)d_in[3];
    const float* W2 = (const float*)d_in[4];
    const float* b2 = (const float*)d_in[5];
    const float* Wo = (const float*)d_in[6];
    const float* bo = (const float*)d_in[7];
    float* out = (float*)d_out;

    char* ws = (char*)d_ws;
    int*   cnt    = (int*)ws;                      ws += 400000;
    int*   fill   = (int*)ws;                      ws += 400000;
    int*   rowptr = (int*)ws;                      ws += 400004 + 60;  // align
    int*   bsum   = (int*)ws;                      ws += 2048;
    float* dis    = (float*)ws;                    ws += 400000;
    int*   esrc   = (int*)ws;                      ws += (size_t)N_EDGES * 4;
    float* eval   = (float*)ws;                    ws += (size_t)N_EDGES * 4;
    float* h      = (float*)ws;                    ws += (size_t)N_NODES * CH * 4;
    float* x1     = (float*)ws;                    ws += (size_t)N_NODES * CH * 4;
    float* x2     = (float*)ws;

    const int B = 256;
    const int gN = (N_NODES + B - 1) / B;
    const int gE = (N_EDGES + B - 1) / B;

    // CSR build (graph-static per call)
    k_init<<<gN, B, 0, stream>>>(cnt, fill);
    k_count<<<gE, B, 0, stream>>>(dst, cnt);
    k_dis<<<gN, B, 0, stream>>>(cnt, dis);
    k_scan1<<<NB_SCAN, 256, 0, stream>>>(cnt, rowptr, bsum);
    k_scan2<<<1, 512, 0, stream>>>(bsum);
    k_scan3<<<NB_SCAN, 256, 0, stream>>>(rowptr, bsum);
    k_scatter<<<gE, B, 0, stream>>>(src, dst, rowptr, fill, dis, esrc, eval);

    // layer 1
    k_gemm128<<<N_NODES / 32, B, 0, stream>>>(x, W1, h);
    k_agg_csr<<<N_NODES / 4, B, 0, stream>>>(rowptr, esrc, eval, h, dis, b1, x1);

    // layer 2
    k_gemm128<<<N_NODES / 32, B, 0, stream>>>(x1, W2, h);
    k_agg_csr<<<N_NODES / 4, B, 0, stream>>>(rowptr, esrc, eval, h, dis, b2, x2);

    // output projection
    k_final<<<N_NODES / 16, B, 0, stream>>>(x1, x2, Wo, bo, out);
}

// Round 3
// 513.791 us; speedup vs baseline: 3.5722x; 1.5681x over previous
//
#include <hip/hip_runtime.h>
#include <hip/hip_fp16.h>

#define N_NODES 100000
#define N_EDGES 1600000
#define CH 128
#define OCH 64
#define NB_SCAN 391  // ceil(100000/256)

typedef _Float16 half8 __attribute__((ext_vector_type(8)));
typedef float f32x4 __attribute__((ext_vector_type(4)));

__device__ __forceinline__ ushort f2h(float f) {
    _Float16 h = (_Float16)f;
    return *(ushort*)&h;
}

// XOR-swizzled f16 offset inside a [rows][128] f16 tile: 8-element groups,
// group index XOR (row&15) -> b128 frag reads and staging writes both hit the
// inherent 8-dword/bank floor (no extra conflicts).
__device__ __forceinline__ int swz(int row, int k) {
    return row * 128 + ((((k >> 3) ^ (row & 15)) << 3) | (k & 7));
}

// ---------------- CSR build ----------------

__global__ void k_init(int* __restrict__ cnt, int* __restrict__ fill) {
    int i = blockIdx.x * blockDim.x + threadIdx.x;
    if (i < N_NODES) { cnt[i] = 0; fill[i] = 0; }
}

__global__ void k_count(const int* __restrict__ dst, int* __restrict__ cnt) {
    int i = blockIdx.x * blockDim.x + threadIdx.x;
    if (i < N_EDGES) atomicAdd(&cnt[dst[i]], 1);
}

// exclusive scan pass 1 (+ fused dis = rsqrt(deg))
__global__ void k_scan1(const int* __restrict__ cnt, int* __restrict__ rowptr,
                        int* __restrict__ bsum, float* __restrict__ dis) {
    __shared__ int tmp[256];
    int i = blockIdx.x * 256 + threadIdx.x;
    int v = (i < N_NODES) ? cnt[i] : 0;
    if (i < N_NODES) dis[i] = rsqrtf((float)(v + 1));  // +1 self-loop
    tmp[threadIdx.x] = v;
    __syncthreads();
    for (int off = 1; off < 256; off <<= 1) {
        int t = (threadIdx.x >= off) ? tmp[threadIdx.x - off] : 0;
        __syncthreads();
        tmp[threadIdx.x] += t;
        __syncthreads();
    }
    if (i < N_NODES) rowptr[i] = tmp[threadIdx.x] - v;
    if (threadIdx.x == 255) bsum[blockIdx.x] = tmp[255];
}

__global__ void k_scan2(int* __restrict__ bsum) {
    __shared__ int tmp[512];
    int v = (threadIdx.x < NB_SCAN) ? bsum[threadIdx.x] : 0;
    tmp[threadIdx.x] = v;
    __syncthreads();
    for (int off = 1; off < 512; off <<= 1) {
        int t = (threadIdx.x >= off) ? tmp[threadIdx.x - off] : 0;
        __syncthreads();
        tmp[threadIdx.x] += t;
        __syncthreads();
    }
    if (threadIdx.x < NB_SCAN) bsum[threadIdx.x] = tmp[threadIdx.x] - v;
}

__global__ void k_scan3(int* __restrict__ rowptr, const int* __restrict__ bsum) {
    int i = blockIdx.x * 256 + threadIdx.x;
    if (i < N_NODES) rowptr[i] += bsum[blockIdx.x];
    if (i == 0) rowptr[N_NODES] = N_EDGES;
}

// packed record: one 8B store per edge (was two 4B random stores)
__global__ void k_scatter(const int* __restrict__ src, const int* __restrict__ dst,
                          const int* __restrict__ rowptr, int* __restrict__ fill,
                          const float* __restrict__ dis, int2* __restrict__ rec) {
    int e = blockIdx.x * blockDim.x + threadIdx.x;
    if (e >= N_EDGES) return;
    int s = src[e], d = dst[e];
    int pos = rowptr[d] + atomicAdd(&fill[d], 1);
    rec[pos] = make_int2(s, __float_as_int(dis[s] * dis[d]));
}

// ---------------- weight prep: W[k][n] f32 -> swizzled W^T f16 LDS-image ----------------

__global__ void k_prepW(const float* __restrict__ W, ushort* __restrict__ out, int ncols) {
    int i = blockIdx.x * blockDim.x + threadIdx.x;
    if (i >= 128 * ncols) return;
    int k = i / ncols, n = i - k * ncols;
    out[swz(n, k)] = f2h(W[i]);
}

// ---------------- MFMA GEMM: out_f16[N][128] = A[N][128] @ W[128][128] ----------------
// block = 256 thr (4 waves), tile 64 rows x 128 cols; full K=128 in LDS.
// wave wv: rows wv*16..+16; 4 k-chunks x 8 n-tiles = 32 mfma_f32_16x16x32_f16.

template <typename IT>
__global__ __launch_bounds__(256) void k_gemm_mfma(const IT* __restrict__ A,
                                                   const ushort* __restrict__ Ws,
                                                   ushort* __restrict__ out) {
    __shared__ ushort sB[128 * 128];  // swizzled W^T
    __shared__ ushort sA[64 * 128];   // swizzled A tile
    const int tid = threadIdx.x;
    const int row0 = blockIdx.x * 64;

    for (int i = tid; i < 2048; i += 256)  // 32KB flat copy
        ((float4*)sB)[i] = ((const float4*)Ws)[i];

    for (int i = tid; i < 2048; i += 256) {  // A: 64 rows x 32 4-elem units
        int m = i >> 5, u = i & 31, k4 = u << 2;
        int r = row0 + m;
        ushort4 pk = make_ushort4(0, 0, 0, 0);
        if (r < N_NODES) {
            if constexpr (sizeof(IT) == 4) {
                float4 a = ((const float4*)A)[r * 32 + u];
                pk = make_ushort4(f2h(a.x), f2h(a.y), f2h(a.z), f2h(a.w));
            } else {
                pk = ((const ushort4*)A)[r * 32 + u];
            }
        }
        *(ushort4*)&sA[swz(m, k4)] = pk;
    }
    __syncthreads();

    const int lane = tid & 63, wv = tid >> 6;
    const int mrow = lane & 15, quad = lane >> 4;
    f32x4 acc[8] = {};
#pragma unroll
    for (int kc = 0; kc < 4; ++kc) {
        int g = kc * 4 + quad;  // k-group index (k>>3)
        half8 a = *(const half8*)&sA[(wv * 16 + mrow) * 128 + ((g ^ mrow) << 3)];
#pragma unroll
        for (int nt = 0; nt < 8; ++nt) {
            half8 b = *(const half8*)&sB[(nt * 16 + mrow) * 128 + ((g ^ mrow) << 3)];
            acc[nt] = __builtin_amdgcn_mfma_f32_16x16x32_f16(a, b, acc[nt], 0, 0, 0);
        }
    }

    const int rbase = row0 + wv * 16 + quad * 4;  // D: row=quad*4+reg, col=lane&15
#pragma unroll
    for (int nt = 0; nt < 8; ++nt) {
#pragma unroll
        for (int rg = 0; rg < 4; ++rg) {
            int r = rbase + rg;
            if (r < N_NODES) out[r * 128 + nt * 16 + mrow] = f2h(acc[nt][rg]);
        }
    }
}

// ---------------- CSR aggregation (fused bias + self-loop + relu), f16 h ----------------

__global__ __launch_bounds__(256) void k_agg(const int* __restrict__ rowptr,
                                             const int2* __restrict__ rec,
                                             const ushort* __restrict__ h,
                                             const float* __restrict__ dis,
                                             const float* __restrict__ bias,
                                             ushort* __restrict__ out) {
    const int v = blockIdx.x * 4 + (threadIdx.x >> 6);
    const int lane = threadIdx.x & 63;
    const __half2* h2 = (const __half2*)h;

    float s = dis[v];
    s = s * s;
    float2 acc = __half22float2(h2[(size_t)v * 64 + lane]);
    float2 bv = *(const float2*)&bias[lane * 2];
    acc.x = acc.x * s + bv.x;
    acc.y = acc.y * s + bv.y;

    int e = rowptr[v], e1 = rowptr[v + 1];
    for (; e + 1 < e1; e += 2) {
        int2 r0 = rec[e], r1 = rec[e + 1];
        float2 t0 = __half22float2(h2[(size_t)r0.x * 64 + lane]);
        float2 t1 = __half22float2(h2[(size_t)r1.x * 64 + lane]);
        float w0 = __int_as_float(r0.y), w1 = __int_as_float(r1.y);
        acc.x += w0 * t0.x + w1 * t1.x;
        acc.y += w0 * t0.y + w1 * t1.y;
    }
    if (e < e1) {
        int2 r0 = rec[e];
        float w0 = __int_as_float(r0.y);
        float2 t0 = __half22float2(h2[(size_t)r0.x * 64 + lane]);
        acc.x += w0 * t0.x;
        acc.y += w0 * t0.y;
    }
    acc.x = fmaxf(acc.x, 0.f);
    acc.y = fmaxf(acc.y, 0.f);
    ((__half2*)out)[(size_t)v * 64 + lane] = __float22half2_rn(acc);
}

// ---------------- final MFMA: out_f32[N][64] = (x1+x2)@Wo + bo ----------------

__global__ __launch_bounds__(256) void k_final_mfma(const ushort* __restrict__ x1,
                                                    const ushort* __restrict__ x2,
                                                    const ushort* __restrict__ Ws,
                                                    const float* __restrict__ bo,
                                                    float* __restrict__ out) {
    __shared__ ushort sB[64 * 128];  // swizzled Wo^T
    __shared__ ushort sA[64 * 128];
    const int tid = threadIdx.x;
    const int row0 = blockIdx.x * 64;

    for (int i = tid; i < 1024; i += 256)
        ((float4*)sB)[i] = ((const float4*)Ws)[i];

    for (int i = tid; i < 2048; i += 256) {
        int m = i >> 5, u = i & 31, k4 = u << 2;
        int r = row0 + m;
        uint2 pk = make_uint2(0, 0);
        if (r < N_NODES) {
            uint2 ua = ((const uint2*)x1)[r * 32 + u];
            uint2 ub = ((const uint2*)x2)[r * 32 + u];
            __half2 s0 = __hadd2(*(__half2*)&ua.x, *(__half2*)&ub.x);
            __half2 s1 = __hadd2(*(__half2*)&ua.y, *(__half2*)&ub.y);
            pk = make_uint2(*(uint*)&s0, *(uint*)&s1);
        }
        *(uint2*)&sA[swz(m, k4)] = pk;
    }
    __syncthreads();

    const int lane = tid & 63, wv = tid >> 6;
    const int mrow = lane & 15, quad = lane >> 4;
    f32x4 acc[4] = {};
#pragma unroll
    for (int kc = 0; kc < 4; ++kc) {
        int g = kc * 4 + quad;
        half8 a = *(const half8*)&sA[(wv * 16 + mrow) * 128 + ((g ^ mrow) << 3)];
#pragma unroll
        for (int nt = 0; nt < 4; ++nt) {
            half8 b = *(const half8*)&sB[(nt * 16 + mrow) * 128 + ((g ^ mrow) << 3)];
            acc[nt] = __builtin_amdgcn_mfma_f32_16x16x32_f16(a, b, acc[nt], 0, 0, 0);
        }
    }

    const int rbase = row0 + wv * 16 + quad * 4;
#pragma unroll
    for (int nt = 0; nt < 4; ++nt) {
        float bb = bo[nt * 16 + mrow];
#pragma unroll
        for (int rg = 0; rg < 4; ++rg) {
            int r = rbase + rg;
            if (r < N_NODES) out[(size_t)r * 64 + nt * 16 + mrow] = acc[nt][rg] + bb;
        }
    }
}

// ---------------- launch ----------------

extern "C" void kernel_launch(void* const* d_in, const int* in_sizes, int n_in,
                              void* d_out, int out_size, void* d_ws, size_t ws_size,
                              hipStream_t stream) {
    const float* x  = (const float*)d_in[0];
    const int*   ei = (const int*)d_in[1];
    const int*   src = ei;
    const int*   dst = ei + N_EDGES;
    const float* W1 = (const float*)d_in[2];
    const float* b1 = (const float*)d_in[3];
    const float* W2 = (const float*)d_in[4];
    const float* b2 = (const float*)d_in[5];
    const float* Wo = (const float*)d_in[6];
    const float* bo = (const float*)d_in[7];
    float* out = (float*)d_out;

    char* ws = (char*)d_ws;
    int*    cnt    = (int*)ws;            ws += 400000;
    int*    fill   = (int*)ws;            ws += 400000;
    int*    rowptr = (int*)ws;            ws += 400064;
    int*    bsum   = (int*)ws;            ws += 2048;
    float*  dis    = (float*)ws;          ws += 400000;  // offset now 1602112 (16-aligned)
    int2*   rec    = (int2*)ws;           ws += (size_t)N_EDGES * 8;
    ushort* W1s    = (ushort*)ws;         ws += 32768;
    ushort* W2s    = (ushort*)ws;         ws += 32768;
    ushort* WoTs   = (ushort*)ws;         ws += 16384;
    ushort* h      = (ushort*)ws;         ws += (size_t)N_NODES * CH * 2;
    ushort* x1     = (ushort*)ws;         ws += (size_t)N_NODES * CH * 2;
    ushort* x2     = (ushort*)ws;

    const int B = 256;
    const int gN = (N_NODES + B - 1) / B;
    const int gE = (N_EDGES + B - 1) / B;
    const int gG = (N_NODES + 63) / 64;  // 1563

    // CSR build + weight prep
    k_init<<<gN, B, 0, stream>>>(cnt, fill);
    k_count<<<gE, B, 0, stream>>>(dst, cnt);
    k_scan1<<<NB_SCAN, 256, 0, stream>>>(cnt, rowptr, bsum, dis);
    k_scan2<<<1, 512, 0, stream>>>(bsum);
    k_scan3<<<NB_SCAN, 256, 0, stream>>>(rowptr, bsum);
    k_scatter<<<gE, B, 0, stream>>>(src, dst, rowptr, fill, dis, rec);
    k_prepW<<<(128 * 128 + B - 1) / B, B, 0, stream>>>(W1, W1s, 128);
    k_prepW<<<(128 * 128 + B - 1) / B, B, 0, stream>>>(W2, W2s, 128);
    k_prepW<<<(128 * 64 + B - 1) / B, B, 0, stream>>>(Wo, WoTs, 64);

    // layer 1
    k_gemm_mfma<float><<<gG, B, 0, stream>>>(x, W1s, h);
    k_agg<<<N_NODES / 4, B, 0, stream>>>(rowptr, rec, h, dis, b1, x1);

    // layer 2
    k_gemm_mfma<ushort><<<gG, B, 0, stream>>>(x1, W2s, h);
    k_agg<<<N_NODES / 4, B, 0, stream>>>(rowptr, rec, h, dis, b2, x2);

    // output projection
    k_final_mfma<<<gG, B, 0, stream>>>(x1, x2, WoTs, bo, out);
}